// Round 5
// baseline (234.771 us; speedup 1.0000x reference)
//
#include <hip/hip_runtime.h>
#include <hip/hip_cooperative_groups.h>
#include <stdint.h>

namespace cg = cooperative_groups;

// Q2Linear, single cooperative kernel.
// Phase 1a: per-row quantize x fp32 -> i8 (one row per wave, register-resident).
// Phase 1b: pack w int32 {-2..1} -> i8 (exact), 16 rows per block.
// grid.sync()
// Phase 2: i8 MFMA GEMM (16x16x64), BK=128 = one scale block, double-buffered
//          LDS via global_load_lds(16B), XOR-swizzled tiles (0 bank conflicts),
//          scales in padded LDS [n][33] (conflict-free both directions),
//          per-row x-scale folded at epilogue.

#define MM 1024
#define NN 4096
#define KK 4096
#define BK 128

typedef __attribute__((ext_vector_type(4))) int intx4;
typedef __attribute__((ext_vector_type(4))) float floatx4;

typedef const __attribute__((address_space(1))) void global_cvoid;
typedef __attribute__((address_space(3))) void lds_void;

__global__ __launch_bounds__(256, 1) void q2_fused(
    const float* __restrict__ x, const int* __restrict__ wq,
    const float* __restrict__ scales, float* __restrict__ out,
    char* __restrict__ xq, float* __restrict__ qrow, char* __restrict__ wb)
{
    __shared__ char As[2][128 * BK];   // 16 KB each
    __shared__ char Bs[2][128 * BK];
    __shared__ float Sl[128 * 33];     // scales [n_local][block], +1 pad

    const int tid  = threadIdx.x;
    const int lane = tid & 63;
    const int wave = tid >> 6;
    const int bid  = blockIdx.x;

    // ================= phase 1a: quantize x (one row per wave) ================
    {
        const int row = bid * 4 + wave;              // 256 blocks * 4 waves = 1024 rows
        const float* xr = x + (size_t)row * KK;
        floatx4 v[16];
        float amax = 0.f;
#pragma unroll
        for (int c = 0; c < 16; ++c) {
            v[c] = *(const floatx4*)(xr + (size_t)(c * 64 + lane) * 4);
#pragma unroll
            for (int e = 0; e < 4; ++e) amax = fmaxf(amax, fabsf(v[c][e]));
        }
#pragma unroll
        for (int off = 32; off; off >>= 1) amax = fmaxf(amax, __shfl_xor(amax, off));
        amax = fmaxf(amax, 1e-20f);
        const float qinv = 127.0f / amax;
        if (lane == 0) qrow[row] = amax / 127.0f;
        char* xo = xq + (size_t)row * KK;
#pragma unroll
        for (int c = 0; c < 16; ++c) {
            int p = 0;
#pragma unroll
            for (int e = 0; e < 4; ++e) {
                float r = rintf(v[c][e] * qinv);
                r = fminf(fmaxf(r, -127.f), 127.f);
                p |= ((int)r & 255) << (8 * e);
            }
            *(int*)(xo + (size_t)(c * 64 + lane) * 4) = p;
        }
    }

    // ================= phase 1b: pack w -> i8 (16 rows per block) =============
    {
#pragma unroll 4
        for (int rr = 0; rr < 16; ++rr) {
            const size_t base = ((size_t)(bid * 16 + rr)) * KK + (size_t)tid * 16;
            const intx4* src = (const intx4*)(wq + base);
            intx4 o;
#pragma unroll
            for (int c = 0; c < 4; ++c) {
                intx4 a = src[c];
                o[c] = (a[0] & 255) | ((a[1] & 255) << 8) |
                       ((a[2] & 255) << 16) | (a[3] << 24);
            }
            *(intx4*)(wb + base) = o;
        }
    }

    __threadfence();
    cg::this_grid().sync();

    // ================= phase 2: i8 MFMA GEMM ==================================
    const int wm   = (wave & 1) * 64;
    const int wn   = (wave >> 1) * 64;
    const int r16  = lane & 15;
    const int quad = lane >> 4;
    const int sw   = r16 & 7;

    // XCD pinning: bid&7 -> XCD; each XCD owns a 512-wide n-strip (2MB i8 L2-resident)
    const int xcd = bid & 7, loc = bid >> 3;
    const int nT = xcd * 4 + (loc & 3);   // 0..31
    const int mT = loc >> 2;              // 0..7
    const int mBase = mT * 128, nBase = nT * 128;

    const int rg = lane >> 3;
    const int cs = (lane & 7) ^ rg;       // address permute -> XOR-swizzled LDS tile
    const char* gA = xq + (size_t)(mBase + wave * 32 + rg) * KK + cs * 16;
    const char* gB = wb + (size_t)(nBase + wave * 32 + rg) * KK + cs * 16;
    const int ldsRow = wave * 32;

    floatx4 facc[4][4];
#pragma unroll
    for (int i = 0; i < 4; ++i)
#pragma unroll
        for (int j = 0; j < 4; ++j) facc[i][j] = (floatx4){0.f, 0.f, 0.f, 0.f};

#define STAGE(BUF, SLAB)                                                        \
    {                                                                           \
        _Pragma("unroll")                                                       \
        for (int t = 0; t < 4; ++t) {                                           \
            __builtin_amdgcn_global_load_lds(                                   \
                (global_cvoid*)(gA + (size_t)(t * 8) * KK + (SLAB) * BK),       \
                (lds_void*)&As[BUF][(ldsRow + t * 8) * BK], 16, 0, 0);          \
            __builtin_amdgcn_global_load_lds(                                   \
                (global_cvoid*)(gB + (size_t)(t * 8) * KK + (SLAB) * BK),       \
                (lds_void*)&Bs[BUF][(ldsRow + t * 8) * BK], 16, 0, 0);          \
        }                                                                       \
    }

#define COMPUTE(BUF, SLAB)                                                      \
    {                                                                           \
        intx4 iacc[4][4];                                                       \
        _Pragma("unroll")                                                       \
        for (int kp = 0; kp < 2; ++kp) {                                        \
            intx4 av[4], bv[4];                                                 \
            _Pragma("unroll")                                                   \
            for (int i = 0; i < 4; ++i)                                         \
                av[i] = *(const intx4*)&As[BUF][(wm + i * 16 + r16) * BK +      \
                                               (((kp * 4 + quad) ^ sw) << 4)];  \
            _Pragma("unroll")                                                   \
            for (int j = 0; j < 4; ++j)                                         \
                bv[j] = *(const intx4*)&Bs[BUF][(wn + j * 16 + r16) * BK +      \
                                               (((kp * 4 + quad) ^ sw) << 4)];  \
            _Pragma("unroll")                                                   \
            for (int i = 0; i < 4; ++i)                                         \
                _Pragma("unroll")                                               \
                for (int j = 0; j < 4; ++j)                                     \
                    iacc[i][j] = __builtin_amdgcn_mfma_i32_16x16x64_i8(         \
                        av[i], bv[j], kp ? iacc[i][j] : (intx4){0, 0, 0, 0},    \
                        0, 0, 0);                                               \
        }                                                                       \
        float sf[4];                                                            \
        _Pragma("unroll")                                                       \
        for (int j = 0; j < 4; ++j) sf[j] = Sl[(wn + j * 16 + r16) * 33 + (SLAB)];\
        _Pragma("unroll")                                                       \
        for (int i = 0; i < 4; ++i)                                             \
            _Pragma("unroll")                                                   \
            for (int j = 0; j < 4; ++j)                                         \
                _Pragma("unroll")                                               \
                for (int r = 0; r < 4; ++r)                                     \
                    facc[i][j][r] += (float)iacc[i][j][r] * sf[j];              \
    }

    STAGE(0, 0)
    // stage scales: coalesced global read, padded-row LDS write (2 lanes/bank = free)
    for (int t = tid; t < 4096; t += 256) {
        int nl = t >> 5, b = t & 31;
        Sl[nl * 33 + b] = scales[(size_t)(nBase + nl) * 32 + b];
    }
    __syncthreads();

    const int NIT = KK / BK;  // 32
    for (int it = 0; it < NIT; it += 2) {
        if (it + 1 < NIT) STAGE(1, it + 1)
        COMPUTE(0, it)
        __syncthreads();
        if (it + 2 < NIT) STAGE(0, it + 2)
        COMPUTE(1, it + 1)
        __syncthreads();
    }

    // epilogue: C/D col = lane&15 (n), row = quad*4 + reg (m); fold q[m]
#pragma unroll
    for (int i = 0; i < 4; ++i) {
        floatx4 qv = *(const floatx4*)(qrow + mBase + wm + i * 16 + quad * 4);
#pragma unroll
        for (int r = 0; r < 4; ++r) {
            int mg = mBase + wm + i * 16 + quad * 4 + r;
            float* orow = out + (size_t)mg * NN + nBase + wn + r16;
#pragma unroll
            for (int j = 0; j < 4; ++j) orow[j * 16] = facc[i][j][r] * qv[r];
        }
    }
#undef STAGE
#undef COMPUTE
}

extern "C" void kernel_launch(void* const* d_in, const int* in_sizes, int n_in,
                              void* d_out, int out_size, void* d_ws, size_t ws_size,
                              hipStream_t stream) {
    const float* x      = (const float*)d_in[0];
    const int*   wq     = (const int*)d_in[1];
    const float* scales = (const float*)d_in[2];
    float*       out    = (float*)d_out;

    char*  xq   = (char*)d_ws;                                   // 4 MB
    float* qrow = (float*)((char*)d_ws + (size_t)MM * KK);       // 4 KB
    char*  wb   = (char*)d_ws + (size_t)MM * KK + 4096;          // 16.8 MB

    void* args[] = {(void*)&x, (void*)&wq, (void*)&scales, (void*)&out,
                    (void*)&xq, (void*)&qrow, (void*)&wb};
    hipLaunchCooperativeKernel(q2_fused, dim3(256), dim3(256), args, 0, stream);
}

// Round 6
// 151.910 us; speedup vs baseline: 1.5455x; 1.5455x over previous
//
#include <hip/hip_runtime.h>
#include <stdint.h>

// Q2Linear int8 path, 3 dispatches (fusion regressed: conv at 1 blk/CU was 4x
// slower than standalone; cooperative launch added replay overhead).
//   quant_x: per-row x fp32 -> i8 (q = rowmax/127)
//   conv_w8: w int32 {-2..1} -> i8 (exact)
//   q8_gemm: i8 MFMA 16x16x64, tile 64(m)x128(n), BK=128 (= one scale block).
//            512 blocks = 2/CU (LDS 48 KB/block) so one block's barrier drain
//            overlaps the other's MFMAs (m114 cross-block overlap — the R4
//            kernel at 1 blk/CU had none, hence 75% stall).
//            Scales read per-slab from global (L1-resident slice), no Sl LDS.

#define MM 1024
#define NN 4096
#define KK 4096
#define BK 128

typedef __attribute__((ext_vector_type(4))) int intx4;
typedef __attribute__((ext_vector_type(4))) float floatx4;

typedef const __attribute__((address_space(1))) void global_cvoid;
typedef __attribute__((address_space(3))) void lds_void;

// ---- quantize x: one row per block ------------------------------------------
__global__ __launch_bounds__(256) void quant_x(const float* __restrict__ x,
                                               char* __restrict__ xq,
                                               float* __restrict__ qrow) {
    const int m   = blockIdx.x;
    const int tid = threadIdx.x;
    const float* xr = x + (size_t)m * KK;
    floatx4 v[4];
    float amax = 0.f;
#pragma unroll
    for (int c = 0; c < 4; ++c) {
        v[c] = *(const floatx4*)(xr + (c * 256 + tid) * 4);
#pragma unroll
        for (int e = 0; e < 4; ++e) amax = fmaxf(amax, fabsf(v[c][e]));
    }
#pragma unroll
    for (int off = 32; off; off >>= 1) amax = fmaxf(amax, __shfl_down(amax, off));
    __shared__ float wmax[4];
    if ((tid & 63) == 0) wmax[tid >> 6] = amax;
    __syncthreads();
    amax = fmaxf(fmaxf(wmax[0], wmax[1]), fmaxf(wmax[2], wmax[3]));
    amax = fmaxf(amax, 1e-20f);
    const float qinv = 127.0f / amax;
    if (tid == 0) qrow[m] = amax / 127.0f;
#pragma unroll
    for (int c = 0; c < 4; ++c) {
        int p = 0;
#pragma unroll
        for (int e = 0; e < 4; ++e) {
            float r = rintf(v[c][e] * qinv);
            r = fminf(fmaxf(r, -127.f), 127.f);
            p |= ((int)r & 255) << (8 * e);
        }
        *(int*)(xq + (size_t)m * KK + (c * 256 + tid) * 4) = p;
    }
}

// ---- pack w -> i8 (exact) ----------------------------------------------------
__global__ __launch_bounds__(256) void conv_w8(const int* __restrict__ wq,
                                               char* __restrict__ wb) {
    int t = blockIdx.x * 256 + threadIdx.x;  // 16 elems per thread
    const intx4* src = (const intx4*)wq + (size_t)t * 4;
    intx4 o;
#pragma unroll
    for (int c = 0; c < 4; ++c) {
        intx4 a = src[c];
        o[c] = (a[0] & 255) | ((a[1] & 255) << 8) | ((a[2] & 255) << 16) | (a[3] << 24);
    }
    *((intx4*)wb + t) = o;
}

// ---- GEMM: 64x128 tile, 4 waves (each 64m x 32n), double-buffered LDS --------
__global__ __launch_bounds__(256) void q8_gemm(const char* __restrict__ xq,
                                               const char* __restrict__ wb,
                                               const float* __restrict__ qrow,
                                               const float* __restrict__ scales,
                                               float* __restrict__ out) {
    __shared__ char As[2][64 * BK];    // 8 KB each
    __shared__ char Bs[2][128 * BK];   // 16 KB each   -> 48 KB total, 2 blocks/CU

    const int tid  = threadIdx.x;
    const int lane = tid & 63;
    const int wave = tid >> 6;
    const int r16  = lane & 15;
    const int quad = lane >> 4;
    const int sw   = r16 & 7;
    const int wn   = wave * 32;        // wave's n offset within tile

    // XCD pinning: bid&7 -> XCD; each XCD owns 4 n-tiles (512 cols, 2MB i8 B-strip)
    const int bid = blockIdx.x;
    const int xcd = bid & 7, loc = bid >> 3;   // loc 0..63
    const int nT = xcd * 4 + (loc & 3);        // 0..31
    const int mT = loc >> 2;                   // 0..15
    const int mBase = mT * 64, nBase = nT * 128;

    // staging address permute -> XOR-swizzled LDS tile (verified, 0 conflicts)
    const int rg = lane >> 3;
    const int cs = (lane & 7) ^ rg;
    const char* gA = xq + (size_t)(mBase + wave * 16 + rg) * KK + cs * 16;
    const char* gB = wb + (size_t)(nBase + wave * 32 + rg) * KK + cs * 16;
    const int ldsRowA = wave * 16;
    const int ldsRowB = wave * 32;

    const float* sBase = scales + (size_t)(nBase + wn + r16) * 32;  // +j*16*32 +slab

    floatx4 facc[4][2];
#pragma unroll
    for (int i = 0; i < 4; ++i)
#pragma unroll
        for (int j = 0; j < 2; ++j) facc[i][j] = (floatx4){0.f, 0.f, 0.f, 0.f};

#define STAGE(BUF, SLAB)                                                        \
    {                                                                           \
        _Pragma("unroll")                                                       \
        for (int t = 0; t < 2; ++t)                                             \
            __builtin_amdgcn_global_load_lds(                                   \
                (global_cvoid*)(gA + (size_t)(t * 8) * KK + (SLAB) * BK),       \
                (lds_void*)&As[BUF][(ldsRowA + t * 8) * BK], 16, 0, 0);         \
        _Pragma("unroll")                                                       \
        for (int t = 0; t < 4; ++t)                                             \
            __builtin_amdgcn_global_load_lds(                                   \
                (global_cvoid*)(gB + (size_t)(t * 8) * KK + (SLAB) * BK),       \
                (lds_void*)&Bs[BUF][(ldsRowB + t * 8) * BK], 16, 0, 0);         \
    }

#define COMPUTE(BUF, SLAB)                                                      \
    {                                                                           \
        float sf0 = sBase[(SLAB)];                                              \
        float sf1 = sBase[16 * 32 + (SLAB)];                                    \
        intx4 iacc[4][2];                                                       \
        _Pragma("unroll")                                                       \
        for (int kp = 0; kp < 2; ++kp) {                                        \
            intx4 av[4], bv[2];                                                 \
            _Pragma("unroll")                                                   \
            for (int i = 0; i < 4; ++i)                                         \
                av[i] = *(const intx4*)&As[BUF][(i * 16 + r16) * BK +           \
                                               (((kp * 4 + quad) ^ sw) << 4)];  \
            _Pragma("unroll")                                                   \
            for (int j = 0; j < 2; ++j)                                         \
                bv[j] = *(const intx4*)&Bs[BUF][(wn + j * 16 + r16) * BK +      \
                                               (((kp * 4 + quad) ^ sw) << 4)];  \
            _Pragma("unroll")                                                   \
            for (int i = 0; i < 4; ++i)                                         \
                _Pragma("unroll")                                               \
                for (int j = 0; j < 2; ++j)                                     \
                    iacc[i][j] = __builtin_amdgcn_mfma_i32_16x16x64_i8(         \
                        av[i], bv[j], kp ? iacc[i][j] : (intx4){0, 0, 0, 0},    \
                        0, 0, 0);                                               \
        }                                                                       \
        _Pragma("unroll")                                                       \
        for (int i = 0; i < 4; ++i)                                             \
            _Pragma("unroll")                                                   \
            for (int r = 0; r < 4; ++r) {                                       \
                facc[i][0][r] += (float)iacc[i][0][r] * sf0;                    \
                facc[i][1][r] += (float)iacc[i][1][r] * sf1;                    \
            }                                                                   \
    }

    STAGE(0, 0)
    __syncthreads();

    const int NIT = KK / BK;  // 32
    for (int it = 0; it < NIT; it += 2) {
        if (it + 1 < NIT) STAGE(1, it + 1)
        COMPUTE(0, it)
        __syncthreads();
        if (it + 2 < NIT) STAGE(0, it + 2)
        COMPUTE(1, it + 1)
        __syncthreads();
    }

    // epilogue: C/D col = lane&15 (n), row = quad*4 + reg (m); fold q[m]
#pragma unroll
    for (int i = 0; i < 4; ++i) {
        floatx4 qv = *(const floatx4*)(qrow + mBase + i * 16 + quad * 4);
#pragma unroll
        for (int r = 0; r < 4; ++r) {
            int mg = mBase + i * 16 + quad * 4 + r;
            float* orow = out + (size_t)mg * NN + nBase + wn + r16;
#pragma unroll
            for (int j = 0; j < 2; ++j) orow[j * 16] = facc[i][j][r] * qv[r];
        }
    }
#undef STAGE
#undef COMPUTE
}

extern "C" void kernel_launch(void* const* d_in, const int* in_sizes, int n_in,
                              void* d_out, int out_size, void* d_ws, size_t ws_size,
                              hipStream_t stream) {
    const float* x      = (const float*)d_in[0];
    const int*   wq     = (const int*)d_in[1];
    const float* scales = (const float*)d_in[2];
    float*       out    = (float*)d_out;

    char*  xq   = (char*)d_ws;                                   // 4 MB
    float* qrow = (float*)((char*)d_ws + (size_t)MM * KK);       // 4 KB
    char*  wb   = (char*)d_ws + (size_t)MM * KK + 4096;          // 16.8 MB

    quant_x<<<MM, 256, 0, stream>>>(x, xq, qrow);
    conv_w8<<<(size_t)NN * KK / 16 / 256, 256, 0, stream>>>(wq, wb);
    q8_gemm<<<(MM / 64) * (NN / 128), 256, 0, stream>>>(xq, wb, qrow, scales, out);
}

// Round 7
// 145.842 us; speedup vs baseline: 1.6098x; 1.0416x over previous
//
#include <hip/hip_runtime.h>
#include <stdint.h>

// Q2Linear int8 path, 2 dispatches.
//   prep:   blocks 0..1023   — per-row quantize x fp32 -> i8 (q = rowmax/127)
//           blocks 1024..5119 — pack w int32 {-2..1} -> i8 (exact), coalesced
//   q8_gemm: i8 MFMA 16x16x64, tile 64(m)x128(n), BK=128 (= one scale block),
//            512 blocks = 2/CU. Scales staged once into padded LDS so the
//            K-loop has NO global loads except global_load_lds — the per-slab
//            rescale no longer drains the vmcnt prefetch queue (R6's stall).

#define MM 1024
#define NN 4096
#define KK 4096
#define BK 128

typedef __attribute__((ext_vector_type(4))) int intx4;
typedef __attribute__((ext_vector_type(4))) float floatx4;

typedef const __attribute__((address_space(1))) void global_cvoid;
typedef __attribute__((address_space(3))) void lds_void;

// ---- prep: quantize x (1 row/block) OR pack w (4096 i8-dwords/block) ---------
__global__ __launch_bounds__(256) void prep(const float* __restrict__ x,
                                            const int* __restrict__ wq,
                                            char* __restrict__ xq,
                                            float* __restrict__ qrow,
                                            char* __restrict__ wb) {
    const int tid = threadIdx.x;
    if (blockIdx.x < MM) {
        // ---- quantize one x row ----
        const int m = blockIdx.x;
        const float* xr = x + (size_t)m * KK;
        floatx4 v[4];
        float amax = 0.f;
#pragma unroll
        for (int c = 0; c < 4; ++c) {
            v[c] = *(const floatx4*)(xr + (c * 256 + tid) * 4);
#pragma unroll
            for (int e = 0; e < 4; ++e) amax = fmaxf(amax, fabsf(v[c][e]));
        }
#pragma unroll
        for (int off = 32; off; off >>= 1) amax = fmaxf(amax, __shfl_down(amax, off));
        __shared__ float wmax[4];
        if ((tid & 63) == 0) wmax[tid >> 6] = amax;
        __syncthreads();
        amax = fmaxf(fmaxf(wmax[0], wmax[1]), fmaxf(wmax[2], wmax[3]));
        amax = fmaxf(amax, 1e-20f);
        const float qinv = 127.0f / amax;
        if (tid == 0) qrow[m] = amax / 127.0f;
#pragma unroll
        for (int c = 0; c < 4; ++c) {
            int p = 0;
#pragma unroll
            for (int e = 0; e < 4; ++e) {
                float r = rintf(v[c][e] * qinv);
                r = fminf(fmaxf(r, -127.f), 127.f);
                p |= ((int)r & 255) << (8 * e);
            }
            *(int*)(xq + (size_t)m * KK + (c * 256 + tid) * 4) = p;
        }
    } else {
        // ---- pack w: fully coalesced (lane-consecutive 16B reads / 4B writes)
        const int blk = blockIdx.x - MM;
#pragma unroll
        for (int c = 0; c < 4; ++c) {
            size_t c4 = (size_t)blk * 1024 + c * 256 + tid;  // intx4-chunk id
            intx4 a = ((const intx4*)wq)[c4];
            ((int*)wb)[c4] = (a[0] & 255) | ((a[1] & 255) << 8) |
                             ((a[2] & 255) << 16) | (a[3] << 24);
        }
    }
}

// ---- GEMM: 64x128 tile, 4 waves (each 64m x 32n), double-buffered LDS --------
__global__ __launch_bounds__(256) void q8_gemm(const char* __restrict__ xq,
                                               const char* __restrict__ wb,
                                               const float* __restrict__ qrow,
                                               const float* __restrict__ scales,
                                               float* __restrict__ out) {
    __shared__ char As[2][64 * BK];    // 8 KB each
    __shared__ char Bs[2][128 * BK];   // 16 KB each
    __shared__ float Sl[128 * 33];     // scales [n_local][block], +1 pad (16.9 KB)
    // total 64.9 KB -> 2 blocks/CU

    const int tid  = threadIdx.x;
    const int lane = tid & 63;
    const int wave = tid >> 6;
    const int r16  = lane & 15;
    const int quad = lane >> 4;
    const int sw   = r16 & 7;
    const int wn   = wave * 32;        // wave's n offset within tile

    // XCD pinning: bid&7 -> XCD; each XCD owns 4 n-tiles (512 cols, 2MB i8 B-strip)
    const int bid = blockIdx.x;
    const int xcd = bid & 7, loc = bid >> 3;   // loc 0..63
    const int nT = xcd * 4 + (loc & 3);        // 0..31
    const int mT = loc >> 2;                   // 0..15
    const int mBase = mT * 64, nBase = nT * 128;

    // staging address permute -> XOR-swizzled LDS tile (verified, 0 conflicts)
    const int rg = lane >> 3;
    const int cs = (lane & 7) ^ rg;
    const char* gA = xq + (size_t)(mBase + wave * 16 + rg) * KK + cs * 16;
    const char* gB = wb + (size_t)(nBase + wave * 32 + rg) * KK + cs * 16;
    const int ldsRowA = wave * 16;
    const int ldsRowB = wave * 32;

    floatx4 facc[4][2];
#pragma unroll
    for (int i = 0; i < 4; ++i)
#pragma unroll
        for (int j = 0; j < 2; ++j) facc[i][j] = (floatx4){0.f, 0.f, 0.f, 0.f};

#define STAGE(BUF, SLAB)                                                        \
    {                                                                           \
        _Pragma("unroll")                                                       \
        for (int t = 0; t < 2; ++t)                                             \
            __builtin_amdgcn_global_load_lds(                                   \
                (global_cvoid*)(gA + (size_t)(t * 8) * KK + (SLAB) * BK),       \
                (lds_void*)&As[BUF][(ldsRowA + t * 8) * BK], 16, 0, 0);         \
        _Pragma("unroll")                                                       \
        for (int t = 0; t < 4; ++t)                                             \
            __builtin_amdgcn_global_load_lds(                                   \
                (global_cvoid*)(gB + (size_t)(t * 8) * KK + (SLAB) * BK),       \
                (lds_void*)&Bs[BUF][(ldsRowB + t * 8) * BK], 16, 0, 0);         \
    }

#define COMPUTE(BUF, SLAB)                                                      \
    {                                                                           \
        float sf0 = Sl[(wn + r16) * 33 + (SLAB)];                               \
        float sf1 = Sl[(wn + 16 + r16) * 33 + (SLAB)];                          \
        intx4 iacc[4][2];                                                       \
        _Pragma("unroll")                                                       \
        for (int kp = 0; kp < 2; ++kp) {                                        \
            intx4 av[4], bv[2];                                                 \
            _Pragma("unroll")                                                   \
            for (int i = 0; i < 4; ++i)                                         \
                av[i] = *(const intx4*)&As[BUF][(i * 16 + r16) * BK +           \
                                               (((kp * 4 + quad) ^ sw) << 4)];  \
            _Pragma("unroll")                                                   \
            for (int j = 0; j < 2; ++j)                                         \
                bv[j] = *(const intx4*)&Bs[BUF][(wn + j * 16 + r16) * BK +      \
                                               (((kp * 4 + quad) ^ sw) << 4)];  \
            _Pragma("unroll")                                                   \
            for (int i = 0; i < 4; ++i)                                         \
                _Pragma("unroll")                                               \
                for (int j = 0; j < 2; ++j)                                     \
                    iacc[i][j] = __builtin_amdgcn_mfma_i32_16x16x64_i8(         \
                        av[i], bv[j], kp ? iacc[i][j] : (intx4){0, 0, 0, 0},    \
                        0, 0, 0);                                               \
        }                                                                       \
        _Pragma("unroll")                                                       \
        for (int i = 0; i < 4; ++i)                                             \
            _Pragma("unroll")                                                   \
            for (int r = 0; r < 4; ++r) {                                       \
                facc[i][0][r] += (float)iacc[i][0][r] * sf0;                    \
                facc[i][1][r] += (float)iacc[i][1][r] * sf1;                    \
            }                                                                   \
    }

    STAGE(0, 0)
    // stage scales once: coalesced global read; LDS banks (nl+b)%32 -> 2-way = free
    for (int t = tid; t < 4096; t += 256) {
        int nl = t >> 5, b = t & 31;
        Sl[nl * 33 + b] = scales[(size_t)(nBase + nl) * 32 + b];
    }
    __syncthreads();

    const int NIT = KK / BK;  // 32
    for (int it = 0; it < NIT; it += 2) {
        if (it + 1 < NIT) STAGE(1, it + 1)
        COMPUTE(0, it)
        __syncthreads();
        if (it + 2 < NIT) STAGE(0, it + 2)
        COMPUTE(1, it + 1)
        __syncthreads();
    }

    // epilogue: C/D col = lane&15 (n), row = quad*4 + reg (m); fold q[m]
#pragma unroll
    for (int i = 0; i < 4; ++i) {
        floatx4 qv = *(const floatx4*)(qrow + mBase + i * 16 + quad * 4);
#pragma unroll
        for (int r = 0; r < 4; ++r) {
            int mg = mBase + i * 16 + quad * 4 + r;
            float* orow = out + (size_t)mg * NN + nBase + wn + r16;
#pragma unroll
            for (int j = 0; j < 2; ++j) orow[j * 16] = facc[i][j][r] * qv[r];
        }
    }
#undef STAGE
#undef COMPUTE
}

extern "C" void kernel_launch(void* const* d_in, const int* in_sizes, int n_in,
                              void* d_out, int out_size, void* d_ws, size_t ws_size,
                              hipStream_t stream) {
    const float* x      = (const float*)d_in[0];
    const int*   wq     = (const int*)d_in[1];
    const float* scales = (const float*)d_in[2];
    float*       out    = (float*)d_out;

    char*  xq   = (char*)d_ws;                                   // 4 MB
    float* qrow = (float*)((char*)d_ws + (size_t)MM * KK);       // 4 KB
    char*  wb   = (char*)d_ws + (size_t)MM * KK + 4096;          // 16.8 MB

    prep<<<MM + (size_t)NN * KK / 16 / 256, 256, 0, stream>>>(x, wq, xq, qrow, wb);
    q8_gemm<<<(MM / 64) * (NN / 128), 256, 0, stream>>>(xq, wb, qrow, scales, out);
}